// Round 1
// baseline (1043.644 us; speedup 1.0000x reference)
//
#include <hip/hip_runtime.h>

typedef _Float16 f16;
typedef _Float16 f16x8 __attribute__((ext_vector_type(8)));
typedef float f32x4 __attribute__((ext_vector_type(4)));

#define T_STEPS 256
#define F_IN 32
#define H_DIM 256
#define G3 768  // 3*H

// d_ws layout:
//   WrP: [48 ntiles][8 kfrags][64 lanes] f16x8   = 384 KB  (rec_kernel fragment-packed)
//   WkP: [48 ntiles][64 lanes] f16x8             =  48 KB  (input kernel fragment-packed)

// Pack fp32 weights into fp16 MFMA B-fragment layout.
// Fragment convention (must match A-frag build in main kernel; any consistent
// within-lane k permutation cancels in the MFMA dot product):
//   lane l, elem e  ->  k = (l>>4)*8 + e  (within a 32-wide k-frag), n = ntile*16 + (l&15)
__global__ void pack_weights_kernel(const float* __restrict__ wk,
                                    const float* __restrict__ wr,
                                    f16x8* __restrict__ wrp,
                                    f16x8* __restrict__ wkp) {
    const int bid = blockIdx.x;
    const int l = threadIdx.x;
    const int lr = l & 15, lq = l >> 4;
    if (bid < 384) {
        const int nt = bid >> 3, kf = bid & 7;
        const int n = nt * 16 + lr;
        f16x8 v;
#pragma unroll
        for (int e = 0; e < 8; ++e) {
            const int k = kf * 32 + lq * 8 + e;
            v[e] = (f16)wr[k * G3 + n];
        }
        wrp[bid * 64 + l] = v;
    } else {
        const int nt = bid - 384;
        const int n = nt * 16 + lr;
        f16x8 v;
#pragma unroll
        for (int e = 0; e < 8; ++e) {
            const int k = lq * 8 + e;  // F_IN = 32 -> exactly one k-frag
            v[e] = (f16)wk[k * G3 + n];
        }
        wkp[nt * 64 + l] = v;
    }
}

// One block = 16 batch rows, 8 waves (512 thr). Wave w owns hidden cols
// j in [32w, 32w+32): its 6 output N-tiles are {z: 2w,2w+1 | r: 16+2w,17+2w | hh: 32+2w,33+2w}
// so z/r/hh for hidden unit j live in the SAME lane -> gating is register-local.
__global__ __launch_bounds__(512, 2) void gru_fused_kernel(
    const float* __restrict__ x,      // [2048][256][32]
    const float* __restrict__ bias,   // [2][768]
    const float* __restrict__ gamma,
    const float* __restrict__ beta,
    const float* __restrict__ mmean,
    const float* __restrict__ mvar,
    const float* __restrict__ dw,     // [256]
    const float* __restrict__ db,     // [1]
    const f16x8* __restrict__ wrp,
    const f16x8* __restrict__ wkp,
    float* __restrict__ out)          // [2048]
{
    __shared__ f16 hbuf[16 * 264];   // h in fp16, row stride 264 (528 B) to break bank conflicts
    __shared__ f16 xbuf[16 * 32];    // x_t tile fp16
    __shared__ float red[8][16];

    const int tid = threadIdx.x;
    const int w = tid >> 6;
    const int l = tid & 63;
    const int lr = l & 15;
    const int lq = l >> 4;
    const int r0 = blockIdx.x * 16;

    const int nt0 = 2 * w;       // z tiles
    const int nt2 = 16 + 2 * w;  // r tiles
    const int nt4 = 32 + 2 * w;  // hh tiles

    // persistent input-projection B fragments (registers, never reloaded)
    const f16x8 xkz0 = wkp[(nt0    ) * 64 + l];
    const f16x8 xkz1 = wkp[(nt0 + 1) * 64 + l];
    const f16x8 xkr0 = wkp[(nt2    ) * 64 + l];
    const f16x8 xkr1 = wkp[(nt2 + 1) * 64 + l];
    const f16x8 xkh0 = wkp[(nt4    ) * 64 + l];
    const f16x8 xkh1 = wkp[(nt4 + 1) * 64 + l];

    // per-lane combined biases (col j depends only on lane, persistent)
    float bz[2], br[2], bxh[2], brh[2];
#pragma unroll
    for (int t2 = 0; t2 < 2; ++t2) {
        const int j = 32 * w + 16 * t2 + lr;
        bz[t2]  = bias[j] + bias[G3 + j];                  // ib_z + rb_z
        br[t2]  = bias[256 + j] + bias[G3 + 256 + j];      // ib_r + rb_r
        bxh[t2] = bias[512 + j];                           // ib_h (outside r*)
        brh[t2] = bias[G3 + 512 + j];                      // rb_h (inside r*)
    }

    // rec-weight fragment pointers: pw[i][kf*64] = frag(ntile i, kfrag kf)
    const f16x8* pw[6];
    pw[0] = wrp + (size_t)nt0 * 512 + l;
    pw[1] = wrp + (size_t)(nt0 + 1) * 512 + l;
    pw[2] = wrp + (size_t)nt2 * 512 + l;
    pw[3] = wrp + (size_t)(nt2 + 1) * 512 + l;
    pw[4] = wrp + (size_t)nt4 * 512 + l;
    pw[5] = wrp + (size_t)(nt4 + 1) * 512 + l;

    for (int i = tid; i < 16 * 264; i += 512) hbuf[i] = (f16)0.f;

    // h state in D-fragment layout: row = lq*4+g, col = 32w + 16*t2 + lr
    f32x4 hr0 = {0.f, 0.f, 0.f, 0.f};
    f32x4 hr1 = {0.f, 0.f, 0.f, 0.f};

    const int xrow = tid >> 5, xf = tid & 31;  // 512 thr == 16 rows * 32 feats
    const float* xptr = x + ((size_t)(r0 + xrow) * T_STEPS) * F_IN + xf;
    float xv = xptr[0];

    const f32x4 fz = {0.f, 0.f, 0.f, 0.f};

    __syncthreads();

    for (int t = 0; t < T_STEPS; ++t) {
        xbuf[xrow * 32 + xf] = (f16)xv;

        // prefetch kf=0 weight frags before the barrier (no LDS dependence)
        f16x8 bwA[6], bwB[6];
#pragma unroll
        for (int i = 0; i < 6; ++i) bwA[i] = pw[i][0];

        __syncthreads();  // barrier1: xbuf ready, hbuf(t-1) writes visible

        // prefetch next x under this step's compute
        {
            const int tn = (t + 1 < T_STEPS) ? (t + 1) : t;
            xv = xptr[tn * F_IN];
        }

        // input projection (K=32, one MFMA per tile); hh x-part kept separate from rec part
        const f16x8 ax = *reinterpret_cast<const f16x8*>(&xbuf[lr * 32 + lq * 8]);
        f32x4 az[2], ar[2], axh[2], arh[2];
        az[0]  = __builtin_amdgcn_mfma_f32_16x16x32_f16(ax, xkz0, fz, 0, 0, 0);
        az[1]  = __builtin_amdgcn_mfma_f32_16x16x32_f16(ax, xkz1, fz, 0, 0, 0);
        ar[0]  = __builtin_amdgcn_mfma_f32_16x16x32_f16(ax, xkr0, fz, 0, 0, 0);
        ar[1]  = __builtin_amdgcn_mfma_f32_16x16x32_f16(ax, xkr1, fz, 0, 0, 0);
        axh[0] = __builtin_amdgcn_mfma_f32_16x16x32_f16(ax, xkh0, fz, 0, 0, 0);
        axh[1] = __builtin_amdgcn_mfma_f32_16x16x32_f16(ax, xkh1, fz, 0, 0, 0);
        arh[0] = fz;
        arh[1] = fz;

        // recurrent matmul, K = 256 = 8 k-frags, double-buffered weight streaming from L2
#pragma unroll
        for (int kf = 0; kf < 8; ++kf) {
            f16x8* curb = (kf & 1) ? bwB : bwA;
            f16x8* nxtb = (kf & 1) ? bwA : bwB;
            if (kf < 7) {
#pragma unroll
                for (int i = 0; i < 6; ++i) nxtb[i] = pw[i][(kf + 1) * 64];
            }
            const f16x8 ah =
                *reinterpret_cast<const f16x8*>(&hbuf[lr * 264 + kf * 32 + lq * 8]);
            az[0]  = __builtin_amdgcn_mfma_f32_16x16x32_f16(ah, curb[0], az[0], 0, 0, 0);
            az[1]  = __builtin_amdgcn_mfma_f32_16x16x32_f16(ah, curb[1], az[1], 0, 0, 0);
            ar[0]  = __builtin_amdgcn_mfma_f32_16x16x32_f16(ah, curb[2], ar[0], 0, 0, 0);
            ar[1]  = __builtin_amdgcn_mfma_f32_16x16x32_f16(ah, curb[3], ar[1], 0, 0, 0);
            arh[0] = __builtin_amdgcn_mfma_f32_16x16x32_f16(ah, curb[4], arh[0], 0, 0, 0);
            arh[1] = __builtin_amdgcn_mfma_f32_16x16x32_f16(ah, curb[5], arh[1], 0, 0, 0);
        }

        // gates (fully lane-local)
        float hn0[4], hn1[4];
#pragma unroll
        for (int g = 0; g < 4; ++g) {
            {
                const float z  = 1.f / (1.f + __expf(-(az[0][g] + bz[0])));
                const float rr = 1.f / (1.f + __expf(-(ar[0][g] + br[0])));
                const float hh = fmaxf(0.f, axh[0][g] + bxh[0] + rr * (arh[0][g] + brh[0]));
                hr0[g] = z * hr0[g] + (1.f - z) * hh;
                hn0[g] = hr0[g];
            }
            {
                const float z  = 1.f / (1.f + __expf(-(az[1][g] + bz[1])));
                const float rr = 1.f / (1.f + __expf(-(ar[1][g] + br[1])));
                const float hh = fmaxf(0.f, axh[1][g] + bxh[1] + rr * (arh[1][g] + brh[1]));
                hr1[g] = z * hr1[g] + (1.f - z) * hh;
                hn1[g] = hr1[g];
            }
        }

        __syncthreads();  // barrier2: all reads of old hbuf/xbuf complete

        // publish new h (fp16) for next step's A-fragments
#pragma unroll
        for (int g = 0; g < 4; ++g) {
            const int m = lq * 4 + g;
            hbuf[m * 264 + (32 * w + lr)]      = (f16)hn0[g];
            hbuf[m * 264 + (32 * w + 16 + lr)] = (f16)hn1[g];
        }
    }

    // epilogue: BatchNorm (inference) + Dense(1), deterministic reduction
    float s[4] = {0.f, 0.f, 0.f, 0.f};
#pragma unroll
    for (int t2 = 0; t2 < 2; ++t2) {
        const int j = 32 * w + 16 * t2 + lr;
        const float scale = gamma[j] * rsqrtf(mvar[j] + 1e-3f);
        const float mn = mmean[j], bt = beta[j], wv = dw[j];
#pragma unroll
        for (int g = 0; g < 4; ++g) {
            const float h = (t2 == 0) ? hr0[g] : hr1[g];
            const float y = (h - mn) * scale + bt;
            s[g] += y * wv;
        }
    }
#pragma unroll
    for (int mask = 1; mask <= 8; mask <<= 1) {
#pragma unroll
        for (int g = 0; g < 4; ++g) s[g] += __shfl_xor(s[g], mask, 64);
    }
    if (lr == 0) {
#pragma unroll
        for (int g = 0; g < 4; ++g) red[w][lq * 4 + g] = s[g];
    }
    __syncthreads();
    if (tid < 16) {
        float o = db[0];
#pragma unroll
        for (int ww = 0; ww < 8; ++ww) o += red[ww][tid];
        out[r0 + tid] = o;
    }
}

extern "C" void kernel_launch(void* const* d_in, const int* in_sizes, int n_in,
                              void* d_out, int out_size, void* d_ws, size_t ws_size,
                              hipStream_t stream) {
    const float* x      = (const float*)d_in[0];
    const float* kern   = (const float*)d_in[1];
    const float* rkern  = (const float*)d_in[2];
    const float* bias   = (const float*)d_in[3];
    const float* gamma  = (const float*)d_in[4];
    const float* beta   = (const float*)d_in[5];
    const float* mmean  = (const float*)d_in[6];
    const float* mvar   = (const float*)d_in[7];
    const float* dw     = (const float*)d_in[8];
    const float* db     = (const float*)d_in[9];
    float* out = (float*)d_out;

    f16x8* wrp = (f16x8*)d_ws;            // 384 KB
    f16x8* wkp = wrp + 48 * 8 * 64;       //  48 KB after

    pack_weights_kernel<<<432, 64, 0, stream>>>(kern, rkern, wrp, wkp);
    gru_fused_kernel<<<128, 512, 0, stream>>>(x, bias, gamma, beta, mmean, mvar,
                                              dw, db, wrp, wkp, out);
}

// Round 2
// 624.840 us; speedup vs baseline: 1.6703x; 1.6703x over previous
//
#include <hip/hip_runtime.h>

typedef _Float16 f16;
typedef _Float16 f16x8 __attribute__((ext_vector_type(8)));
typedef float f32x4 __attribute__((ext_vector_type(4)));

#define T_STEPS 256
#define F_IN 32
#define G3 768   // 3*H
#define HSTR 264 // hbuf row stride (f16) — 528 B, breaks pow2 bank pattern

// d_ws layout:
//   WrP: [48 ntiles][8 kfrags][64 lanes] f16x8 = 384 KB  (rec_kernel fragments)
//   WkP: [48 ntiles][64 lanes] f16x8           =  48 KB  (input kernel fragments)
// Fragment convention (A and B identical, permutation cancels in MFMA):
//   lane l, elem e -> k = (l>>4)*8 + e (within 32-wide kfrag), n = ntile*16 + (l&15)
__global__ void pack_weights_kernel(const float* __restrict__ wk,
                                    const float* __restrict__ wr,
                                    f16x8* __restrict__ wrp,
                                    f16x8* __restrict__ wkp) {
    const int bid = blockIdx.x;
    const int l = threadIdx.x;
    const int lr = l & 15, lq = l >> 4;
    if (bid < 384) {
        const int nt = bid >> 3, kf = bid & 7;
        const int n = nt * 16 + lr;
        f16x8 v;
#pragma unroll
        for (int e = 0; e < 8; ++e) {
            const int k = kf * 32 + lq * 8 + e;
            v[e] = (f16)wr[k * G3 + n];
        }
        wrp[bid * 64 + l] = v;
    } else {
        const int nt = bid - 384;
        const int n = nt * 16 + lr;
        f16x8 v;
#pragma unroll
        for (int e = 0; e < 8; ++e) {
            const int k = lq * 8 + e;
            v[e] = (f16)wk[k * G3 + n];
        }
        wkp[nt * 64 + l] = v;
    }
}

// One block = 16 batch rows, 8 waves. Wave w owns hidden cols [32w, 32w+32):
// N-tiles {z: 2w,2w+1 | r: 16+2w,.. | hh: 32+2w,..} so z/r/hh of a hidden unit
// share a lane -> gating is register-local.
// Rec weights live ENTIRELY in registers: W[6][8] f16x8 = 192 VGPR/lane
// (= 384 KB/block, the whole matrix). No per-step global/L2 traffic.
__global__ __launch_bounds__(512, 2) void gru_fused_kernel(
    const float* __restrict__ x,      // [2048][256][32]
    const float* __restrict__ bias,   // [2][768]
    const float* __restrict__ gamma,
    const float* __restrict__ beta,
    const float* __restrict__ mmean,
    const float* __restrict__ mvar,
    const float* __restrict__ dw,     // [256]
    const float* __restrict__ db,     // [1]
    const f16x8* __restrict__ wrp,
    const f16x8* __restrict__ wkp,
    float* __restrict__ out)          // [2048]
{
    __shared__ __align__(16) f16 hbuf[2][16 * HSTR];  // ping-pong h (fp16)
    __shared__ __align__(16) f16 xbuf[2][16 * 32];    // ping-pong x_t
    __shared__ f16x8 wkl[48 * 64];                    // input-proj B-frags, 48 KB
    __shared__ float red[8][16];

    const int tid = threadIdx.x;
    const int w = tid >> 6;
    const int l = tid & 63;
    const int lr = l & 15;
    const int lq = l >> 4;
    const int r0 = blockIdx.x * 16;

    // this wave's 6 N-tiles: i=0,1 z | 2,3 r | 4,5 hh ; group g uses i = g, 2+g, 4+g
    const int nt[6] = {2 * w, 2 * w + 1, 16 + 2 * w, 16 + 2 * w + 1,
                       32 + 2 * w, 32 + 2 * w + 1};

    // ---- rec weights -> registers (one-time, 48 x global_load_dwordx4) ----
    f16x8 W[6][8];
#pragma unroll
    for (int i = 0; i < 6; ++i)
#pragma unroll
        for (int kf = 0; kf < 8; ++kf)
            W[i][kf] = wrp[((size_t)nt[i] * 8 + kf) * 64 + l];

    // ---- input-proj frags -> LDS (one-time 48 KB) ----
    for (int i = tid; i < 48 * 64; i += 512) wkl[i] = wkp[i];

    // per-lane combined biases (col j = 32w + 16g + lr)
    float bz[2], br[2], bxh[2], brh[2];
#pragma unroll
    for (int g = 0; g < 2; ++g) {
        const int j = 32 * w + 16 * g + lr;
        bz[g]  = bias[j] + bias[G3 + j];
        br[g]  = bias[256 + j] + bias[G3 + 256 + j];
        bxh[g] = bias[512 + j];
        brh[g] = bias[G3 + 512 + j];
    }

    for (int i = tid; i < 16 * HSTR; i += 512) hbuf[0][i] = (f16)0.f;

    const int xrow = tid >> 5, xf = tid & 31;
    const float* xptr = x + ((size_t)(r0 + xrow) * T_STEPS) * F_IN + xf;
    xbuf[0][xrow * 32 + xf] = (f16)xptr[0];
    float xv = xptr[F_IN];  // x at t=1

    f32x4 hr[2];
    hr[0] = {0.f, 0.f, 0.f, 0.f};
    hr[1] = {0.f, 0.f, 0.f, 0.f};
    const f32x4 fz = {0.f, 0.f, 0.f, 0.f};

    __syncthreads();

    for (int t = 0; t < T_STEPS; ++t) {
        const int cur = t & 1, nxt = cur ^ 1;

        // publish x for step t+1 into the nxt buffer (no reader this iter),
        // then issue the t+2 prefetch so HBM latency hides under compute
        xbuf[nxt][xrow * 32 + xf] = (f16)xv;
        {
            const int tn = (t + 2 < T_STEPS) ? (t + 2) : (T_STEPS - 1);
            xv = xptr[(size_t)tn * F_IN];
        }

        const f16x8 ax = *reinterpret_cast<const f16x8*>(&xbuf[cur][lr * 32 + lq * 8]);

        // two 16-col groups sequentially: acc stays at 4 f32x4, and group0's
        // hbuf write between groups blocks LDS-load CSE (keeps VGPRs <= 256)
#pragma unroll
        for (int g = 0; g < 2; ++g) {
            f32x4 az  = __builtin_amdgcn_mfma_f32_16x16x32_f16(ax, wkl[nt[g]     * 64 + l], fz, 0, 0, 0);
            f32x4 ar_ = __builtin_amdgcn_mfma_f32_16x16x32_f16(ax, wkl[nt[2 + g] * 64 + l], fz, 0, 0, 0);
            f32x4 axh = __builtin_amdgcn_mfma_f32_16x16x32_f16(ax, wkl[nt[4 + g] * 64 + l], fz, 0, 0, 0);
            f32x4 arh = fz;
#pragma unroll
            for (int kf = 0; kf < 8; ++kf) {
                const f16x8 ah =
                    *reinterpret_cast<const f16x8*>(&hbuf[cur][lr * HSTR + kf * 32 + lq * 8]);
                az  = __builtin_amdgcn_mfma_f32_16x16x32_f16(ah, W[g][kf],     az,  0, 0, 0);
                ar_ = __builtin_amdgcn_mfma_f32_16x16x32_f16(ah, W[2 + g][kf], ar_, 0, 0, 0);
                arh = __builtin_amdgcn_mfma_f32_16x16x32_f16(ah, W[4 + g][kf], arh, 0, 0, 0);
            }
            // gates: fully lane-local; write h_{t+1} into nxt buffer immediately
            // (ping-pong + end-of-iter barrier make this race-free)
#pragma unroll
            for (int gg = 0; gg < 4; ++gg) {
                const float z  = 1.f / (1.f + __expf(-(az[gg] + bz[g])));
                const float rr = 1.f / (1.f + __expf(-(ar_[gg] + br[g])));
                const float hh = fmaxf(0.f, axh[gg] + bxh[g] + rr * (arh[gg] + brh[g]));
                const float hn = z * hr[g][gg] + (1.f - z) * hh;
                hr[g][gg] = hn;
                hbuf[nxt][(lq * 4 + gg) * HSTR + 32 * w + 16 * g + lr] = (f16)hn;
            }
        }

        __syncthreads();  // writes to nxt visible; all reads of cur done
    }

    // epilogue: BatchNorm (inference) + Dense(1), deterministic reduction
    float s[4] = {0.f, 0.f, 0.f, 0.f};
#pragma unroll
    for (int g = 0; g < 2; ++g) {
        const int j = 32 * w + 16 * g + lr;
        const float scale = gamma[j] * rsqrtf(mvar[j] + 1e-3f);
        const float mn = mmean[j], bt = beta[j], wv = dw[j];
#pragma unroll
        for (int gg = 0; gg < 4; ++gg) {
            const float y = (hr[g][gg] - mn) * scale + bt;
            s[gg] += y * wv;
        }
    }
#pragma unroll
    for (int mask = 1; mask <= 8; mask <<= 1) {
#pragma unroll
        for (int gg = 0; gg < 4; ++gg) s[gg] += __shfl_xor(s[gg], mask, 64);
    }
    if (lr == 0) {
#pragma unroll
        for (int gg = 0; gg < 4; ++gg) red[w][lq * 4 + gg] = s[gg];
    }
    __syncthreads();
    if (tid < 16) {
        float o = db[0];
#pragma unroll
        for (int ww = 0; ww < 8; ++ww) o += red[ww][tid];
        out[r0 + tid] = o;
    }
}

extern "C" void kernel_launch(void* const* d_in, const int* in_sizes, int n_in,
                              void* d_out, int out_size, void* d_ws, size_t ws_size,
                              hipStream_t stream) {
    const float* x      = (const float*)d_in[0];
    const float* kern   = (const float*)d_in[1];
    const float* rkern  = (const float*)d_in[2];
    const float* bias   = (const float*)d_in[3];
    const float* gamma  = (const float*)d_in[4];
    const float* beta   = (const float*)d_in[5];
    const float* mmean  = (const float*)d_in[6];
    const float* mvar   = (const float*)d_in[7];
    const float* dw     = (const float*)d_in[8];
    const float* db     = (const float*)d_in[9];
    float* out = (float*)d_out;

    f16x8* wrp = (f16x8*)d_ws;        // 384 KB
    f16x8* wkp = wrp + 48 * 8 * 64;   //  48 KB after

    pack_weights_kernel<<<432, 64, 0, stream>>>(kern, rkern, wrp, wkp);
    gru_fused_kernel<<<128, 512, 0, stream>>>(x, bias, gamma, beta, mmean, mvar,
                                              dw, db, wrp, wkp, out);
}

// Round 3
// 453.318 us; speedup vs baseline: 2.3022x; 1.3784x over previous
//
#include <hip/hip_runtime.h>

typedef _Float16 f16;
typedef _Float16 f16x8 __attribute__((ext_vector_type(8)));
typedef float f32x4 __attribute__((ext_vector_type(4)));

#define T_STEPS 256
#define F_IN 32
#define G3 768   // 3*H
#define HSTR 264 // hbuf row stride (f16) — 528 B, breaks pow2 bank pattern
#define L2E 1.442695040888963f

// d_ws layout:
//   WrP: [48 ntiles][8 kfrags][64 lanes] f16x8 = 384 KB  (rec_kernel fragments)
//   WkP: [48 ntiles][64 lanes] f16x8           =  48 KB  (input kernel fragments)
// Fragment convention (A and B identical, permutation cancels in MFMA):
//   lane l, elem e -> k = (l>>4)*8 + e (within 32-wide kfrag), n = ntile*16 + (l&15)
__global__ void pack_weights_kernel(const float* __restrict__ wk,
                                    const float* __restrict__ wr,
                                    f16x8* __restrict__ wrp,
                                    f16x8* __restrict__ wkp) {
    const int bid = blockIdx.x;
    const int l = threadIdx.x;
    const int lr = l & 15, lq = l >> 4;
    if (bid < 384) {
        const int nt = bid >> 3, kf = bid & 7;
        const int n = nt * 16 + lr;
        f16x8 v;
#pragma unroll
        for (int e = 0; e < 8; ++e) {
            const int k = kf * 32 + lq * 8 + e;
            v[e] = (f16)wr[k * G3 + n];
        }
        wrp[bid * 64 + l] = v;
    } else {
        const int nt = bid - 384;
        const int n = nt * 16 + lr;
        f16x8 v;
#pragma unroll
        for (int e = 0; e < 8; ++e) {
            const int k = lq * 8 + e;
            v[e] = (f16)wk[k * G3 + n];
        }
        wkp[nt * 64 + l] = v;
    }
}

// One block = 16 batch rows, 8 waves. Wave w owns hidden cols [32w, 32w+32):
// N-tiles {z: 2w,2w+1 | r: 16+2w,.. | hh: 32+2w,..} -> z/r/hh of a hidden unit
// share a lane; gating is register-local.
// Register budget (256/lane at 2 waves/SIMD): 5 weight tiles in regs/AGPR
// (5*8 f16x8 = 160), 6th tile (hh1) in LDS (64 KB), working set ~70 VGPR.
__global__ __launch_bounds__(512, 2) void gru_fused_kernel(
    const float* __restrict__ x,      // [2048][256][32]
    const float* __restrict__ bias,   // [2][768]
    const float* __restrict__ gamma,
    const float* __restrict__ beta,
    const float* __restrict__ mmean,
    const float* __restrict__ mvar,
    const float* __restrict__ dw,     // [256]
    const float* __restrict__ db,     // [1]
    const f16x8* __restrict__ wrp,
    const f16x8* __restrict__ wkp,
    float* __restrict__ out)          // [2048]
{
    __shared__ __align__(16) f16 hbuf[2][16 * HSTR];  // ping-pong h (fp16), 16.9 KB
    __shared__ __align__(16) f16 xbuf[2][16 * 32];    // ping-pong x_t, 2 KB
    __shared__ f16x8 wkl[48 * 64];                    // input-proj B-frags, 48 KB
    __shared__ f16x8 wl5[8][8][64];                   // hh1 tile per wave, 64 KB
    __shared__ float red[8][16];

    const int tid = threadIdx.x;
    const int w = tid >> 6;
    const int l = tid & 63;
    const int lr = l & 15;
    const int lq = l >> 4;
    const int r0 = blockIdx.x * 16;

    // this wave's 6 N-tiles: z0 z1 r0 r1 hh0 hh1
    const int nt[6] = {2 * w, 2 * w + 1, 16 + 2 * w, 16 + 2 * w + 1,
                       32 + 2 * w, 32 + 2 * w + 1};

    // ---- 5 weight tiles -> registers (40 x 16B loads), hh1 tile -> LDS ----
    f16x8 W[5][8];
#pragma unroll
    for (int i = 0; i < 5; ++i)
#pragma unroll
        for (int kf = 0; kf < 8; ++kf)
            W[i][kf] = wrp[((size_t)nt[i] * 8 + kf) * 64 + l];
#pragma unroll
    for (int kf = 0; kf < 8; ++kf)
        wl5[w][kf][l] = wrp[((size_t)nt[5] * 8 + kf) * 64 + l];

    // ---- input-proj frags -> LDS (48 KB) ----
    for (int i = tid; i < 48 * 64; i += 512) wkl[i] = wkp[i];

    // per-lane biases (col j = 32w + 16g + lr); z/r pre-negated for __expf(-x)
    float nbz[2], nbr[2], bxh[2], brh[2];
#pragma unroll
    for (int g = 0; g < 2; ++g) {
        const int j = 32 * w + 16 * g + lr;
        nbz[g] = -(bias[j] + bias[G3 + j]);
        nbr[g] = -(bias[256 + j] + bias[G3 + 256 + j]);
        bxh[g] = bias[512 + j];
        brh[g] = bias[G3 + 512 + j];
    }

    for (int i = tid; i < 16 * HSTR; i += 512) hbuf[0][i] = (f16)0.f;

    const int xrow = tid >> 5, xf = tid & 31;
    const float* xptr = x + ((size_t)(r0 + xrow) * T_STEPS) * F_IN + xf;
    xbuf[0][xrow * 32 + xf] = (f16)xptr[0];
    float xv = xptr[F_IN];  // x at t=1

    f32x4 hr[2];
    hr[0] = {0.f, 0.f, 0.f, 0.f};
    hr[1] = {0.f, 0.f, 0.f, 0.f};
    const f32x4 fz = {0.f, 0.f, 0.f, 0.f};

    __syncthreads();

    for (int t = 0; t < T_STEPS; ++t) {
        const int cur = t & 1, nxt = cur ^ 1;

        // publish x for t+1 into nxt buffer (no reader this iter), prefetch t+2
        xbuf[nxt][xrow * 32 + xf] = (f16)xv;
        {
            const int tn = (t + 2 < T_STEPS) ? (t + 2) : (T_STEPS - 1);
            xv = xptr[(size_t)tn * F_IN];
        }

        const f16x8 ax = *reinterpret_cast<const f16x8*>(&xbuf[cur][lr * 32 + lq * 8]);

        // input projection: 6 MFMA (K=32)
        f32x4 az[2], ar[2], axh[2], arh[2];
        az[0]  = __builtin_amdgcn_mfma_f32_16x16x32_f16(ax, wkl[nt[0] * 64 + l], fz, 0, 0, 0);
        az[1]  = __builtin_amdgcn_mfma_f32_16x16x32_f16(ax, wkl[nt[1] * 64 + l], fz, 0, 0, 0);
        ar[0]  = __builtin_amdgcn_mfma_f32_16x16x32_f16(ax, wkl[nt[2] * 64 + l], fz, 0, 0, 0);
        ar[1]  = __builtin_amdgcn_mfma_f32_16x16x32_f16(ax, wkl[nt[3] * 64 + l], fz, 0, 0, 0);
        axh[0] = __builtin_amdgcn_mfma_f32_16x16x32_f16(ax, wkl[nt[4] * 64 + l], fz, 0, 0, 0);
        axh[1] = __builtin_amdgcn_mfma_f32_16x16x32_f16(ax, wkl[nt[5] * 64 + l], fz, 0, 0, 0);
        arh[0] = fz;
        arh[1] = fz;

        // recurrent matmul: kf OUTER so each ah frag is read once;
        // 6 independent acc chains (dep distance 6 MFMAs > MFMA latency)
#pragma unroll
        for (int kf = 0; kf < 8; ++kf) {
            const f16x8 ah =
                *reinterpret_cast<const f16x8*>(&hbuf[cur][lr * HSTR + kf * 32 + lq * 8]);
            const f16x8 w5 = wl5[w][kf][l];
            az[0]  = __builtin_amdgcn_mfma_f32_16x16x32_f16(ah, W[0][kf], az[0],  0, 0, 0);
            az[1]  = __builtin_amdgcn_mfma_f32_16x16x32_f16(ah, W[1][kf], az[1],  0, 0, 0);
            ar[0]  = __builtin_amdgcn_mfma_f32_16x16x32_f16(ah, W[2][kf], ar[0],  0, 0, 0);
            ar[1]  = __builtin_amdgcn_mfma_f32_16x16x32_f16(ah, W[3][kf], ar[1],  0, 0, 0);
            arh[0] = __builtin_amdgcn_mfma_f32_16x16x32_f16(ah, W[4][kf], arh[0], 0, 0, 0);
            arh[1] = __builtin_amdgcn_mfma_f32_16x16x32_f16(ah, w5,       arh[1], 0, 0, 0);
        }

        // gates: lane-local; sigmoid via v_rcp (1 inst) instead of precise div
#pragma unroll
        for (int g = 0; g < 2; ++g) {
#pragma unroll
            for (int gg = 0; gg < 4; ++gg) {
                const float ez = __expf(fmaf(az[g][gg], -1.f, nbz[g]));
                const float z  = __builtin_amdgcn_rcpf(1.f + ez);
                const float er = __expf(fmaf(ar[g][gg], -1.f, nbr[g]));
                const float rr = __builtin_amdgcn_rcpf(1.f + er);
                const float hh = fmaxf(0.f, fmaf(rr, arh[g][gg] + brh[g], axh[g][gg] + bxh[g]));
                const float hn = fmaf(z, hr[g][gg] - hh, hh);  // z*h + (1-z)*hh
                hr[g][gg] = hn;
                hbuf[nxt][(lq * 4 + gg) * HSTR + 32 * w + 16 * g + lr] = (f16)hn;
            }
        }

        __syncthreads();  // writes to nxt visible; all reads of cur done
    }

    // epilogue: BatchNorm (inference) + Dense(1), deterministic reduction
    float s[4] = {0.f, 0.f, 0.f, 0.f};
#pragma unroll
    for (int g = 0; g < 2; ++g) {
        const int j = 32 * w + 16 * g + lr;
        const float scale = gamma[j] * rsqrtf(mvar[j] + 1e-3f);
        const float mn = mmean[j], bt = beta[j], wv = dw[j];
#pragma unroll
        for (int gg = 0; gg < 4; ++gg) {
            const float y = (hr[g][gg] - mn) * scale + bt;
            s[gg] += y * wv;
        }
    }
#pragma unroll
    for (int mask = 1; mask <= 8; mask <<= 1) {
#pragma unroll
        for (int gg = 0; gg < 4; ++gg) s[gg] += __shfl_xor(s[gg], mask, 64);
    }
    if (lr == 0) {
#pragma unroll
        for (int gg = 0; gg < 4; ++gg) red[w][lq * 4 + gg] = s[gg];
    }
    __syncthreads();
    if (tid < 16) {
        float o = db[0];
#pragma unroll
        for (int ww = 0; ww < 8; ++ww) o += red[ww][tid];
        out[r0 + tid] = o;
    }
}

extern "C" void kernel_launch(void* const* d_in, const int* in_sizes, int n_in,
                              void* d_out, int out_size, void* d_ws, size_t ws_size,
                              hipStream_t stream) {
    const float* x      = (const float*)d_in[0];
    const float* kern   = (const float*)d_in[1];
    const float* rkern  = (const float*)d_in[2];
    const float* bias   = (const float*)d_in[3];
    const float* gamma  = (const float*)d_in[4];
    const float* beta   = (const float*)d_in[5];
    const float* mmean  = (const float*)d_in[6];
    const float* mvar   = (const float*)d_in[7];
    const float* dw     = (const float*)d_in[8];
    const float* db     = (const float*)d_in[9];
    float* out = (float*)d_out;

    f16x8* wrp = (f16x8*)d_ws;        // 384 KB
    f16x8* wkp = wrp + 48 * 8 * 64;   //  48 KB after

    pack_weights_kernel<<<432, 64, 0, stream>>>(kern, rkern, wrp, wkp);
    gru_fused_kernel<<<128, 512, 0, stream>>>(x, bias, gamma, beta, mmean, mvar,
                                              dw, db, wrp, wkp, out);
}